// Round 1
// baseline (255.481 us; speedup 1.0000x reference)
//
#include <hip/hip_runtime.h>

// Problem dims (fixed): B=2, L=512, H_IN=768, E=256, N=12.  M = B*L = 1024.
// out[b,i,n,j] = sum_e key[b,i,e,n]*t[b,j,e]
//              + sum_e relu(su[b,i,e]+tv[b,j,e]+f2b[e])*f3W[n,e] + f3b[n]
// where s=relu(x sW^T+sb), t=relu(x tW^T+tb), key=s blW^T (reshaped E,N minor),
//       su=s Wu^T, tv=t Wv^T  (Wu=f2W[:,:256], Wv=f2W[:,256:]).

// ---------------- generic fp32 tiled GEMM:  C = act(A(MxK,lda) * B(NxK,ldb)^T + bias) ----------------
template<bool RELU, bool BIAS>
__global__ __launch_bounds__(256)
void gemm_nt(const float* __restrict__ A, int lda,
             const float* __restrict__ B, int ldb,
             const float* __restrict__ bias,
             float* __restrict__ C, int ldc, int K)
{
    __shared__ float As[16 * 68];   // [k][m], padded row 68 (16B-aligned rows, 2-way-max banks)
    __shared__ float Bs[16 * 68];   // [k][n]
    const int tid = threadIdx.x;
    const int m0 = blockIdx.y * 64;
    const int n0 = blockIdx.x * 64;
    const int tm = tid >> 4, tn = tid & 15;   // 16x16 threads, 4x4 outputs each
    const int mr = tid >> 2, kq = tid & 3;    // staging: 64 rows x 4 float4

    float acc[4][4];
#pragma unroll
    for (int i = 0; i < 4; ++i)
#pragma unroll
        for (int j = 0; j < 4; ++j) acc[i][j] = 0.f;

    for (int k0 = 0; k0 < K; k0 += 16) {
        __syncthreads();
        float4 av = *reinterpret_cast<const float4*>(&A[(size_t)(m0 + mr) * lda + k0 + kq * 4]);
        float4 bv = *reinterpret_cast<const float4*>(&B[(size_t)(n0 + mr) * ldb + k0 + kq * 4]);
        As[(kq * 4 + 0) * 68 + mr] = av.x;
        As[(kq * 4 + 1) * 68 + mr] = av.y;
        As[(kq * 4 + 2) * 68 + mr] = av.z;
        As[(kq * 4 + 3) * 68 + mr] = av.w;
        Bs[(kq * 4 + 0) * 68 + mr] = bv.x;
        Bs[(kq * 4 + 1) * 68 + mr] = bv.y;
        Bs[(kq * 4 + 2) * 68 + mr] = bv.z;
        Bs[(kq * 4 + 3) * 68 + mr] = bv.w;
        __syncthreads();
#pragma unroll
        for (int kk = 0; kk < 16; ++kk) {
            float a[4], b[4];
            *reinterpret_cast<float4*>(a) = *reinterpret_cast<const float4*>(&As[kk * 68 + tm * 4]);
            *reinterpret_cast<float4*>(b) = *reinterpret_cast<const float4*>(&Bs[kk * 68 + tn * 4]);
#pragma unroll
            for (int i = 0; i < 4; ++i)
#pragma unroll
                for (int j = 0; j < 4; ++j)
                    acc[i][j] = fmaf(a[i], b[j], acc[i][j]);
        }
    }

#pragma unroll
    for (int i = 0; i < 4; ++i) {
#pragma unroll
        for (int j = 0; j < 4; ++j) {
            float v = acc[i][j];
            if (BIAS) v += bias[n0 + tn * 4 + j];
            if (RELU) v = fmaxf(v, 0.f);
            C[(size_t)(m0 + tm * 4 + i) * ldc + n0 + tn * 4 + j] = v;
        }
    }
}

// ---------------- fused output kernel ----------------
// grid (16,16,2): block = (b, i-tile 32, j-tile 32). 256 threads: thread = (ii, jg),
// owns pairs (ii, jg+8p) p=0..3, accumulates 4x12 fp32.
__global__ __launch_bounds__(256)
void fused_out_kernel(const float* __restrict__ KEY,  // [1024][256*12]  (e major, n minor)
                      const float* __restrict__ T,    // [1024][256]
                      const float* __restrict__ SU,   // [1024][256]
                      const float* __restrict__ TV,   // [1024][256]
                      const float* __restrict__ f2b,  // [256]
                      const float* __restrict__ f3W,  // [12][256]
                      const float* __restrict__ f3b,  // [12]
                      float* __restrict__ out)        // [2][512][12][512]
{
    __shared__ float keyc[32 * 196];   // [ii][ee*12+n], row stride 196 (=192+4: banks ii*4, 16B rows)
    __shared__ float tc  [32 * 20];    // [jj][ee], stride 20 (16B-aligned, distinct banks)
    __shared__ float tvc [32 * 20];
    __shared__ float suc [32 * 20];    // [ii][ee]
    __shared__ float f3t [256 * 12];   // f3t[e*12+n] = f3W[n][e]   (broadcast reads)
    __shared__ float f2bc[256];
    __shared__ float f3bc[12];

    const int tid = threadIdx.x;
    const int b  = blockIdx.z;
    const int i0 = blockIdx.y * 32;
    const int j0 = blockIdx.x * 32;
    const int ii = tid >> 3;   // 0..31
    const int jg = tid & 7;    // 0..7

    // one-time staging of constants
#pragma unroll
    for (int r = 0; r < 12; ++r) {
        int idx = tid + 256 * r;        // 0..3071
        int e = idx / 12, n = idx - e * 12;
        f3t[idx] = f3W[n * 256 + e];
    }
    f2bc[tid] = f2b[tid];
    if (tid < 12) f3bc[tid] = f3b[tid];

    float acc[4][12];
#pragma unroll
    for (int p = 0; p < 4; ++p)
#pragma unroll
        for (int n = 0; n < 12; ++n) acc[p][n] = 0.f;

    for (int e0 = 0; e0 < 256; e0 += 16) {
        __syncthreads();
        // stage key[i0..i0+31, e0..e0+15, 0..11]: 6144 floats = 1536 float4, 6 per thread
#pragma unroll
        for (int r = 0; r < 6; ++r) {
            int f = tid + 256 * r;             // 0..1535
            int kii = f / 48;                  // 48 float4 per i-row
            int rem = f - kii * 48;
            float4 v = *reinterpret_cast<const float4*>(
                &KEY[((size_t)(b * 512 + i0 + kii) * 256 + e0) * 12 + rem * 4]);
            *reinterpret_cast<float4*>(&keyc[kii * 196 + rem * 4]) = v;
        }
        {
            int q   = tid & 127;
            int jj  = q >> 2;
            int rem = q & 3;
            if (tid < 128) {
                *reinterpret_cast<float4*>(&tc[jj * 20 + rem * 4]) =
                    *reinterpret_cast<const float4*>(&T[(size_t)(b * 512 + j0 + jj) * 256 + e0 + rem * 4]);
                *reinterpret_cast<float4*>(&suc[jj * 20 + rem * 4]) =
                    *reinterpret_cast<const float4*>(&SU[(size_t)(b * 512 + i0 + jj) * 256 + e0 + rem * 4]);
            } else {
                *reinterpret_cast<float4*>(&tvc[jj * 20 + rem * 4]) =
                    *reinterpret_cast<const float4*>(&TV[(size_t)(b * 512 + j0 + jj) * 256 + e0 + rem * 4]);
            }
        }
        __syncthreads();

        for (int ee = 0; ee < 16; ++ee) {
            float kn[12], fv[12];
            const float* kp = &keyc[ii * 196 + ee * 12];
            *reinterpret_cast<float4*>(&kn[0]) = *reinterpret_cast<const float4*>(kp + 0);
            *reinterpret_cast<float4*>(&kn[4]) = *reinterpret_cast<const float4*>(kp + 4);
            *reinterpret_cast<float4*>(&kn[8]) = *reinterpret_cast<const float4*>(kp + 8);
            const float* fp = &f3t[(e0 + ee) * 12];
            *reinterpret_cast<float4*>(&fv[0]) = *reinterpret_cast<const float4*>(fp + 0);
            *reinterpret_cast<float4*>(&fv[4]) = *reinterpret_cast<const float4*>(fp + 4);
            *reinterpret_cast<float4*>(&fv[8]) = *reinterpret_cast<const float4*>(fp + 8);
            float sui = suc[ii * 20 + ee];
            float f2v = f2bc[e0 + ee];
#pragma unroll
            for (int p = 0; p < 4; ++p) {
                int jj = jg + 8 * p;
                float tval = tc[jj * 20 + ee];
                float h = sui + tvc[jj * 20 + ee] + f2v;
                h = fmaxf(h, 0.f);
#pragma unroll
                for (int n = 0; n < 12; ++n)
                    acc[p][n] += kn[n] * tval + h * fv[n];
            }
        }
    }

    // out[((b*512 + i)*12 + n)*512 + j],  j = j0 + jg + 8p
    const size_t obase = ((size_t)(b * 512 + i0 + ii)) * 12 * 512 + j0 + jg;
#pragma unroll
    for (int n = 0; n < 12; ++n) {
        float fb = f3bc[n];
#pragma unroll
        for (int p = 0; p < 4; ++p)
            out[obase + (size_t)n * 512 + 8 * p] = acc[p][n] + fb;
    }
}

extern "C" void kernel_launch(void* const* d_in, const int* in_sizes, int n_in,
                              void* d_out, int out_size, void* d_ws, size_t ws_size,
                              hipStream_t stream)
{
    const float* x   = (const float*)d_in[0];  // [2,512,768]
    const float* sW  = (const float*)d_in[1];  // [256,768]
    const float* sb  = (const float*)d_in[2];  // [256]
    const float* tW  = (const float*)d_in[3];  // [256,768]
    const float* tb  = (const float*)d_in[4];  // [256]
    const float* f2W = (const float*)d_in[5];  // [256,512]
    const float* f2b = (const float*)d_in[6];  // [256]
    const float* f3W = (const float*)d_in[7];  // [12,256]
    const float* f3b = (const float*)d_in[8];  // [12]
    const float* blW = (const float*)d_in[9];  // [3072,256]
    float* out = (float*)d_out;

    // workspace layout (fp32): S 1024x256 | T 1024x256 | KEY 1024x3072 | SU 1024x256 | TV 1024x256
    // total = 4096*1024*4 B = 16.78 MB
    float* S   = (float*)d_ws;
    float* Tt  = S   + 1024 * 256;
    float* KEY = Tt  + 1024 * 256;
    float* SU  = KEY + 1024 * 3072;
    float* TV  = SU  + 1024 * 256;

    dim3 blk(256);
    // s = relu(x sW^T + sb), t = relu(x tW^T + tb)
    gemm_nt<true,  true ><<<dim3(4, 16), blk, 0, stream>>>(x, 768, sW, 768, sb, S,  256, 768);
    gemm_nt<true,  true ><<<dim3(4, 16), blk, 0, stream>>>(x, 768, tW, 768, tb, Tt, 256, 768);
    // key = s blW^T   (N = 3072 = e*12+n)
    gemm_nt<false, false><<<dim3(48, 16), blk, 0, stream>>>(S, 256, blW, 256, nullptr, KEY, 3072, 256);
    // su = s Wu^T, tv = t Wv^T   (Wu = f2W[:, :256], Wv = f2W[:, 256:], ldb = 512)
    gemm_nt<false, false><<<dim3(4, 16), blk, 0, stream>>>(S,  256, f2W,       512, nullptr, SU, 256, 256);
    gemm_nt<false, false><<<dim3(4, 16), blk, 0, stream>>>(Tt, 256, f2W + 256, 512, nullptr, TV, 256, 256);
    // fused out1 + out2
    fused_out_kernel<<<dim3(16, 16, 2), blk, 0, stream>>>(KEY, Tt, SU, TV, f2b, f3W, f3b, out);
}

// Round 3
// 76.753 us; speedup vs baseline: 3.3286x; 3.3286x over previous
//
#include <hip/hip_runtime.h>
#include <hip/hip_bf16.h>

// B=2, L=512, H_IN=768, E=256, N=12. M = B*L = 1024.
// out[b,i,n,j] = sum_e key[b,i,e,n]*t[b,j,e]
//             + sum_e relu(su[b,i,e]+tv[b,j,e]+f2b[e])*f3W[n,e] + f3b[n]

typedef unsigned short u16;
typedef __attribute__((ext_vector_type(8)))  short   s16x8;
typedef __attribute__((ext_vector_type(8)))  __bf16  bf16x8;
typedef __attribute__((ext_vector_type(4)))  float   f32x4;

__device__ inline u16 f2bf(float f) {
    unsigned u = __builtin_bit_cast(unsigned, f);
    u = (u + 0x7fffu + ((u >> 16) & 1u)) >> 16;
    return (u16)u;
}
__device__ inline unsigned pack2bf(float lo, float hi) {
    return (unsigned)f2bf(lo) | ((unsigned)f2bf(hi) << 16);
}

__device__ inline f32x4 mfma_bf16(s16x8 a, s16x8 b, f32x4 c) {
    return __builtin_amdgcn_mfma_f32_16x16x32_bf16(
        __builtin_bit_cast(bf16x8, a), __builtin_bit_cast(bf16x8, b), c, 0, 0, 0);
}

// ---------------- conversion / permutation kernel (float4-wide) ----------------
__global__ __launch_bounds__(256)
void conv_kernel(const float* __restrict__ x, const float* __restrict__ sW,
                 const float* __restrict__ tW, const float* __restrict__ sb,
                 const float* __restrict__ tb, const float* __restrict__ f2W,
                 const float* __restrict__ blW, const float* __restrict__ f3W,
                 u16* __restrict__ xb, u16* __restrict__ wstb, float* __restrict__ sbtb,
                 u16* __restrict__ blkw, u16* __restrict__ f2wvb, u16* __restrict__ f3wb)
{
    int idx = blockIdx.x * 256 + threadIdx.x;
    if (idx >= 525440) return;
    float4 v;
    u16* dst;
    if (idx < 196608) {                       // xb
        v = *(const float4*)&x[idx * 4];
        dst = &xb[idx * 4];
    } else if (idx < 294912) {                // wstb: rows 0..255 sW, 256..511 tW
        int i4 = (idx - 196608) * 4;
        int row = i4 / 768, k = i4 - row * 768;
        const float* src = (row < 256) ? &sW[row * 768 + k] : &tW[(row - 256) * 768 + k];
        v = *(const float4*)src;
        dst = &wstb[i4];
    } else if (idx < 295040) {                // sbtb f32
        int i4 = (idx - 294912) * 4;
        float4 s = (i4 < 256) ? *(const float4*)&sb[i4] : *(const float4*)&tb[i4 - 256];
        *(float4*)&sbtb[i4] = s;
        return;
    } else if (idx < 508032) {                // blkw [3328][256]: r<3072: n=r>>8,e=r&255 <- blW[e*12+n]; else Wu
        int i4 = (idx - 295040) * 4;
        int r = i4 >> 8, k = i4 & 255;
        const float* src;
        if (r < 3072) { int n = r >> 8, e = r & 255; src = &blW[(e * 12 + n) * 256 + k]; }
        else           { src = &f2W[(r - 3072) * 512 + k]; }
        v = *(const float4*)src;
        dst = &blkw[i4];
    } else if (idx < 524416) {                // f2wvb [256][256] = f2W[:,256:]
        int i4 = (idx - 508032) * 4;
        int e = i4 >> 8, k = i4 & 255;
        v = *(const float4*)&f2W[e * 512 + 256 + k];
        dst = &f2wvb[i4];
    } else {                                  // f3wb [16][256], rows 12..15 zero
        int i4 = (idx - 524416) * 4;
        int row = i4 >> 8, e = i4 & 255;
        if (row < 12) v = *(const float4*)&f3W[row * 256 + e];
        else          v = make_float4(0.f, 0.f, 0.f, 0.f);
        dst = &f3wb[i4];
    }
    ushort4 o;
    o.x = f2bf(v.x); o.y = f2bf(v.y); o.z = f2bf(v.z); o.w = f2bf(v.w);
    *(ushort4*)dst = o;
}

// ---------------- bf16 MFMA GEMM: C = epilogue(A[M][K] * BT[N][K]^T) ----------------
// 64x64 tile, BK=32, 256 threads (4 waves, 32x32 quadrant each, 2x2 16x16 frags)
template<int MODE>
__global__ __launch_bounds__(256, 2)
void gemm_mfma(const u16* __restrict__ A, int lda,
               const u16* __restrict__ BT, int ldb,
               const float* __restrict__ bias,
               void* __restrict__ out0, void* __restrict__ out1p, int K)
{
    __shared__ u16 As[64 * 40];
    __shared__ u16 Bs[64 * 40];
    const int tid = threadIdx.x;
    const int m0 = blockIdx.y * 64, n0 = blockIdx.x * 64;
    const int w = tid >> 6, l = tid & 63;
    const int wr = (w >> 1) * 32, wc = (w & 1) * 32;
    const int lr = l & 15, lg = l >> 4;
    const int srow = tid >> 2, kq = tid & 3;

    f32x4 acc[2][2] = {};
    for (int k0 = 0; k0 < K; k0 += 32) {
        __syncthreads();
        s16x8 av = *(const s16x8*)&A [(size_t)(m0 + srow) * lda + k0 + kq * 8];
        s16x8 bv = *(const s16x8*)&BT[(size_t)(n0 + srow) * ldb + k0 + kq * 8];
        *(s16x8*)&As[srow * 40 + kq * 8] = av;
        *(s16x8*)&Bs[srow * 40 + kq * 8] = bv;
        __syncthreads();
        s16x8 af[2], bf[2];
        af[0] = *(const s16x8*)&As[(wr      + lr) * 40 + lg * 8];
        af[1] = *(const s16x8*)&As[(wr + 16 + lr) * 40 + lg * 8];
        bf[0] = *(const s16x8*)&Bs[(wc      + lr) * 40 + lg * 8];
        bf[1] = *(const s16x8*)&Bs[(wc + 16 + lr) * 40 + lg * 8];
#pragma unroll
        for (int fi = 0; fi < 2; ++fi)
#pragma unroll
            for (int fj = 0; fj < 2; ++fj)
                acc[fi][fj] = mfma_bf16(af[fi], bf[fj], acc[fi][fj]);
    }
#pragma unroll
    for (int fi = 0; fi < 2; ++fi) {
#pragma unroll
        for (int fj = 0; fj < 2; ++fj) {
#pragma unroll
            for (int r = 0; r < 4; ++r) {
                int grow = m0 + wr + fi * 16 + lg * 4 + r;
                int gcol = n0 + wc + fj * 16 + lr;
                float v = acc[fi][fj][r];
                if (MODE == 0) {
                    v = fmaxf(v + bias[gcol], 0.f);
                    ((u16*)out0)[(size_t)grow * 512 + gcol] = f2bf(v);
                } else if (MODE == 1) {
                    if (gcol < 3072) {
                        int n = gcol >> 8, e = gcol & 255;
                        ((u16*)out0)[(size_t)n * 262144 + (size_t)grow * 256 + e] = f2bf(v);
                    } else {
                        ((float*)out1p)[(size_t)grow * 256 + (gcol - 3072)] = v;
                    }
                } else {
                    ((float*)out0)[(size_t)grow * 256 + gcol] = v + bias[gcol];
                }
            }
        }
    }
}

// ---------------- fused output kernel ----------------
// grid (8,16,2): (j-tile 64, i-tile 32, b). 512 threads = 8 waves.
__global__ __launch_bounds__(512, 2)
void fused_out(const u16* __restrict__ KEYP, const u16* __restrict__ STb,
               const float* __restrict__ SU, const float* __restrict__ TV,
               const u16* __restrict__ F3WB, const float* __restrict__ f3b,
               float* __restrict__ out)
{
    __shared__ __align__(16) char smem[58112];
    u16*   keyc = (u16*)smem;              // [12][32][40] bf16
    u16*   tc   = (u16*)(smem + 30720);    // [64][40]
    float* suc  = (float*)(smem + 35840);  // [32][36]
    float* tvc  = (float*)(smem + 40448);  // [64][36]
    u16*   f3c  = (u16*)(smem + 49664);    // [16][264]
    float* mg   = (float*)smem;            // merge reuse [6][2088]

    const int tid = threadIdx.x;
    const int w = tid >> 6, l = tid & 63;
    const int b  = blockIdx.z;
    const int i0 = blockIdx.y * 32;
    const int j0 = blockIdx.x * 64;
    const int lr = l & 15, lg = l >> 4;
    const int q1 = w >> 1, fi = w & 1;          // out1 roles
    const int ig = w & 1, jjs = (w >> 1) * 16;  // out2 roles

    { // stage f3c once (read after first in-loop barrier)
        int r = tid >> 5, q = tid & 31;
        *(s16x8*)&f3c[r * 264 + q * 8] = *(const s16x8*)&F3WB[r * 256 + q * 8];
    }

    f32x4 acc1[3][4] = {};
    f32x4 acc2[16]   = {};

    for (int e0 = 0; e0 < 256; e0 += 32) {
        __syncthreads();
        // key: 1536 16B granules (12n x 32i x 4)
#pragma unroll
        for (int rr = 0; rr < 3; ++rr) {
            int g = tid + 512 * rr;
            int n = g >> 7, ii = (g >> 2) & 31, qq = g & 3;
            *(s16x8*)&keyc[(n * 32 + ii) * 40 + qq * 8] =
                *(const s16x8*)&KEYP[(size_t)n * 262144 + (size_t)(b * 512 + i0 + ii) * 256 + e0 + qq * 8];
        }
        if (tid < 256) {   // t tile (bf16, cols 256.. of STb)
            int rrow = tid >> 2, qq = tid & 3;
            *(s16x8*)&tc[rrow * 40 + qq * 8] =
                *(const s16x8*)&STb[(size_t)(b * 512 + j0 + rrow) * 512 + 256 + e0 + qq * 8];
        } else {           // su tile (f32)
            int u = tid - 256, rrow = u >> 3, qq = u & 7;
            *(f32x4*)&suc[rrow * 36 + qq * 4] =
                *(const f32x4*)&SU[(size_t)(b * 512 + i0 + rrow) * 256 + e0 + qq * 4];
        }
        {                  // tv' tile (f32, f2b already added)
            int rrow = tid >> 3, qq = tid & 7;
            *(f32x4*)&tvc[rrow * 36 + qq * 4] =
                *(const f32x4*)&TV[(size_t)(b * 512 + j0 + rrow) * 256 + e0 + qq * 4];
        }
        __syncthreads();

        // ---- out1: 12 mfma ----
        s16x8 tf[4];
#pragma unroll
        for (int fj = 0; fj < 4; ++fj)
            tf[fj] = *(const s16x8*)&tc[(fj * 16 + lr) * 40 + lg * 8];
#pragma unroll
        for (int a = 0; a < 3; ++a) {
            int n = 3 * q1 + a;
            s16x8 kf = *(const s16x8*)&keyc[(n * 32 + fi * 16 + lr) * 40 + lg * 8];
#pragma unroll
            for (int fj = 0; fj < 4; ++fj)
                acc1[a][fj] = mfma_bf16(kf, tf[fj], acc1[a][fj]);
        }

        // ---- out2: h in-register + 16 mfma ----
        f32x4 s0 = *(const f32x4*)&suc[(ig * 16 + lr) * 36 + lg * 8];
        f32x4 s1 = *(const f32x4*)&suc[(ig * 16 + lr) * 36 + lg * 8 + 4];
        s16x8 f3fr = *(const s16x8*)&f3c[lr * 264 + e0 + lg * 8];
#pragma unroll
        for (int jj = 0; jj < 16; ++jj) {
            int j = jjs + jj;
            f32x4 t0 = *(const f32x4*)&tvc[j * 36 + lg * 8];
            f32x4 t1 = *(const f32x4*)&tvc[j * 36 + lg * 8 + 4];
            float h0 = fmaxf(s0[0] + t0[0], 0.f), h1 = fmaxf(s0[1] + t0[1], 0.f);
            float h2 = fmaxf(s0[2] + t0[2], 0.f), h3 = fmaxf(s0[3] + t0[3], 0.f);
            float h4 = fmaxf(s1[0] + t1[0], 0.f), h5 = fmaxf(s1[1] + t1[1], 0.f);
            float h6 = fmaxf(s1[2] + t1[2], 0.f), h7 = fmaxf(s1[3] + t1[3], 0.f);
            union { s16x8 v; unsigned u[4]; } hp;
            hp.u[0] = pack2bf(h0, h1);
            hp.u[1] = pack2bf(h2, h3);
            hp.u[2] = pack2bf(h4, h5);
            hp.u[3] = pack2bf(h6, h7);
            acc2[jj] = mfma_bf16(hp.v, f3fr, acc2[jj]);
        }
    }

    // ---- merge out2 (D[pair][n]) into out1 layout via LDS, then store ----
#pragma unroll
    for (int nc = 0; nc < 2; ++nc) {
        __syncthreads();
        int nbase = nc * 6;
        if (lr >= nbase && lr < nbase + 6) {
#pragma unroll
            for (int jj = 0; jj < 16; ++jj) {
#pragma unroll
                for (int r = 0; r < 4; ++r) {
                    int i = ig * 16 + lg * 4 + r;
                    mg[(lr - nbase) * 2088 + i * 65 + (jjs + jj)] = acc2[jj][r];
                }
            }
        }
        __syncthreads();
        if ((q1 >> 1) == nc) {
#pragma unroll
            for (int a = 0; a < 3; ++a) {
                int n = 3 * q1 + a;
                float fb = f3b[n];
#pragma unroll
                for (int fj = 0; fj < 4; ++fj) {
#pragma unroll
                    for (int r = 0; r < 4; ++r) {
                        int i = fi * 16 + lg * 4 + r;
                        int j = fj * 16 + lr;
                        float v = acc1[a][fj][r] + mg[(n - nbase) * 2088 + i * 65 + j] + fb;
                        out[(((size_t)(b * 512 + i0 + i)) * 12 + n) * 512 + j0 + j] = v;
                    }
                }
            }
        }
    }
}

extern "C" void kernel_launch(void* const* d_in, const int* in_sizes, int n_in,
                              void* d_out, int out_size, void* d_ws, size_t ws_size,
                              hipStream_t stream)
{
    const float* x   = (const float*)d_in[0];
    const float* sW  = (const float*)d_in[1];
    const float* sb  = (const float*)d_in[2];
    const float* tW  = (const float*)d_in[3];
    const float* tb  = (const float*)d_in[4];
    const float* f2W = (const float*)d_in[5];
    const float* f2b = (const float*)d_in[6];
    const float* f3W = (const float*)d_in[7];
    const float* f3b = (const float*)d_in[8];
    const float* blW = (const float*)d_in[9];
    float* out = (float*)d_out;

    char* p = (char*)d_ws;
    u16*   xb    = (u16*)p;   p += 1572864;   // [1024][768] bf16
    u16*   wstb  = (u16*)p;   p += 786432;    // [512][768] bf16 (sW;tW)
    float* sbtb  = (float*)p; p += 2048;      // [512] f32
    u16*   STb   = (u16*)p;   p += 1048576;   // [1024][512] bf16 (s|t)
    u16*   blkw  = (u16*)p;   p += 1703936;   // [3328][256] bf16 (blW perm ; Wu)
    u16*   KEYP  = (u16*)p;   p += 6291456;   // [12][1024][256] bf16
    float* SUp   = (float*)p; p += 1048576;   // [1024][256] f32
    u16*   f2wvb = (u16*)p;   p += 131072;    // [256][256] bf16 (Wv)
    float* TVp   = (float*)p; p += 1048576;   // [1024][256] f32 (tv + f2b)
    u16*   f3wbg = (u16*)p;   p += 8192;      // [16][256] bf16 (f3W zero-padded)

    conv_kernel<<<2053, 256, 0, stream>>>(x, sW, tW, sb, tb, f2W, blW, f3W,
                                          xb, wstb, sbtb, blkw, f2wvb, f3wbg);
    gemm_mfma<0><<<dim3(8, 16),  256, 0, stream>>>(xb, 768, wstb, 768, sbtb, STb, nullptr, 768);
    gemm_mfma<1><<<dim3(52, 16), 256, 0, stream>>>(STb, 512, blkw, 256, nullptr, KEYP, SUp, 256);
    gemm_mfma<2><<<dim3(4, 16),  256, 0, stream>>>(STb + 256, 512, f2wvb, 256, f2b, TVp, nullptr, 256);
    fused_out<<<dim3(8, 16, 2), 512, 0, stream>>>(KEYP, STb, SUp, TVp, f3wbg, f3b, out);
}

// Round 4
// 69.692 us; speedup vs baseline: 3.6658x; 1.1013x over previous
//
#include <hip/hip_runtime.h>
#include <hip/hip_bf16.h>

// B=2, L=512, H_IN=768, E=256, N=12. M = B*L = 1024.
// out[b,i,n,j] = sum_e key[b,i,e,n]*t[b,j,e]
//             + sum_e relu(su[b,i,e]+tv[b,j,e]+f2b[e])*f3W[n,e] + f3b[n]

typedef unsigned short u16;
typedef __attribute__((ext_vector_type(8)))  short   s16x8;
typedef __attribute__((ext_vector_type(8)))  __bf16  bf16x8;
typedef __attribute__((ext_vector_type(4)))  float   f32x4;

__device__ inline u16 f2bf(float f) {
    unsigned u = __builtin_bit_cast(unsigned, f);
    u = (u + 0x7fffu + ((u >> 16) & 1u)) >> 16;
    return (u16)u;
}

__device__ inline f32x4 mfma_bf16(s16x8 a, s16x8 b, f32x4 c) {
    return __builtin_amdgcn_mfma_f32_16x16x32_bf16(
        __builtin_bit_cast(bf16x8, a), __builtin_bit_cast(bf16x8, b), c, 0, 0, 0);
}
__device__ inline f32x4 mfma_bf16v(bf16x8 a, s16x8 b, f32x4 c) {
    return __builtin_amdgcn_mfma_f32_16x16x32_bf16(
        a, __builtin_bit_cast(bf16x8, b), c, 0, 0, 0);
}

// ---------------- conversion / permutation kernel (float4-wide) ----------------
__global__ __launch_bounds__(256)
void conv_kernel(const float* __restrict__ x, const float* __restrict__ sW,
                 const float* __restrict__ tW, const float* __restrict__ sb,
                 const float* __restrict__ tb, const float* __restrict__ f2W,
                 const float* __restrict__ blW, const float* __restrict__ f3W,
                 u16* __restrict__ xb, u16* __restrict__ wstb, float* __restrict__ sbtb,
                 u16* __restrict__ blkw, u16* __restrict__ f2wvb, u16* __restrict__ f3wb)
{
    int idx = blockIdx.x * 256 + threadIdx.x;
    if (idx >= 525440) return;
    float4 v;
    u16* dst;
    if (idx < 196608) {                       // xb
        v = *(const float4*)&x[idx * 4];
        dst = &xb[idx * 4];
    } else if (idx < 294912) {                // wstb: rows 0..255 sW, 256..511 tW
        int i4 = (idx - 196608) * 4;
        int row = i4 / 768, k = i4 - row * 768;
        const float* src = (row < 256) ? &sW[row * 768 + k] : &tW[(row - 256) * 768 + k];
        v = *(const float4*)src;
        dst = &wstb[i4];
    } else if (idx < 295040) {                // sbtb f32
        int i4 = (idx - 294912) * 4;
        float4 s = (i4 < 256) ? *(const float4*)&sb[i4] : *(const float4*)&tb[i4 - 256];
        *(float4*)&sbtb[i4] = s;
        return;
    } else if (idx < 508032) {                // blkw [3328][256]: r<3072: n=r>>8,e=r&255 <- blW[e*12+n]; else Wu
        int i4 = (idx - 295040) * 4;
        int r = i4 >> 8, k = i4 & 255;
        const float* src;
        if (r < 3072) { int n = r >> 8, e = r & 255; src = &blW[(e * 12 + n) * 256 + k]; }
        else           { src = &f2W[(r - 3072) * 512 + k]; }
        v = *(const float4*)src;
        dst = &blkw[i4];
    } else if (idx < 524416) {                // f2wvb [256][256] = f2W[:,256:]
        int i4 = (idx - 508032) * 4;
        int e = i4 >> 8, k = i4 & 255;
        v = *(const float4*)&f2W[e * 512 + 256 + k];
        dst = &f2wvb[i4];
    } else {                                  // f3wb [16][256], rows 12..15 zero
        int i4 = (idx - 524416) * 4;
        int row = i4 >> 8, e = i4 & 255;
        if (row < 12) v = *(const float4*)&f3W[row * 256 + e];
        else          v = make_float4(0.f, 0.f, 0.f, 0.f);
        dst = &f3wb[i4];
    }
    ushort4 o;
    o.x = f2bf(v.x); o.y = f2bf(v.y); o.z = f2bf(v.z); o.w = f2bf(v.w);
    *(ushort4*)dst = o;
}

// ---------------- bf16 MFMA GEMM: C = epilogue(A[M][K] * BT[N][K]^T) ----------------
// 64x64 tile, BK=64, 256 threads (4 waves, 32x32 quadrant each, 2x2 16x16 frags)
template<int MODE>
__global__ __launch_bounds__(256, 2)
void gemm_mfma(const u16* __restrict__ A, int lda,
               const u16* __restrict__ BT, int ldb,
               const float* __restrict__ bias,
               void* __restrict__ out0, void* __restrict__ out1p, int K)
{
    __shared__ u16 As[64 * 72];   // row pad 72 u16 (144B): bank start 4*row, floor-spread
    __shared__ u16 Bs[64 * 72];
    const int tid = threadIdx.x;
    const int m0 = blockIdx.y * 64, n0 = blockIdx.x * 64;
    const int w = tid >> 6, l = tid & 63;
    const int wr = (w >> 1) * 32, wc = (w & 1) * 32;
    const int lr = l & 15, lg = l >> 4;
    const int srow = tid >> 2, kq = tid & 3;

    f32x4 acc[2][2] = {};
    for (int k0 = 0; k0 < K; k0 += 64) {
        __syncthreads();
        const u16* ap = &A [(size_t)(m0 + srow) * lda + k0];
        const u16* bp = &BT[(size_t)(n0 + srow) * ldb + k0];
        *(s16x8*)&As[srow * 72 + kq * 8]       = *(const s16x8*)&ap[kq * 8];
        *(s16x8*)&As[srow * 72 + (kq + 4) * 8] = *(const s16x8*)&ap[(kq + 4) * 8];
        *(s16x8*)&Bs[srow * 72 + kq * 8]       = *(const s16x8*)&bp[kq * 8];
        *(s16x8*)&Bs[srow * 72 + (kq + 4) * 8] = *(const s16x8*)&bp[(kq + 4) * 8];
        __syncthreads();
#pragma unroll
        for (int kk = 0; kk < 64; kk += 32) {
            s16x8 af[2], bf[2];
            af[0] = *(const s16x8*)&As[(wr      + lr) * 72 + kk + lg * 8];
            af[1] = *(const s16x8*)&As[(wr + 16 + lr) * 72 + kk + lg * 8];
            bf[0] = *(const s16x8*)&Bs[(wc      + lr) * 72 + kk + lg * 8];
            bf[1] = *(const s16x8*)&Bs[(wc + 16 + lr) * 72 + kk + lg * 8];
#pragma unroll
            for (int fi = 0; fi < 2; ++fi)
#pragma unroll
                for (int fj = 0; fj < 2; ++fj)
                    acc[fi][fj] = mfma_bf16(af[fi], bf[fj], acc[fi][fj]);
        }
    }
#pragma unroll
    for (int fi = 0; fi < 2; ++fi) {
#pragma unroll
        for (int fj = 0; fj < 2; ++fj) {
#pragma unroll
            for (int r = 0; r < 4; ++r) {
                int grow = m0 + wr + fi * 16 + lg * 4 + r;
                int gcol = n0 + wc + fj * 16 + lr;
                float v = acc[fi][fj][r];
                if (MODE == 0) {
                    v = fmaxf(v + bias[gcol], 0.f);
                    ((u16*)out0)[(size_t)grow * 512 + gcol] = f2bf(v);
                } else if (MODE == 1) {
                    if (gcol < 3072) {
                        int n = gcol >> 8, e = gcol & 255;
                        ((u16*)out0)[(size_t)n * 262144 + (size_t)grow * 256 + e] = f2bf(v);
                    } else {
                        ((float*)out1p)[(size_t)grow * 256 + (gcol - 3072)] = v;
                    }
                } else {
                    ((float*)out0)[(size_t)grow * 256 + gcol] = v + bias[gcol];
                }
            }
        }
    }
}

// ---------------- fused output kernel ----------------
// grid (16,16,2): (j-tile 32, i-tile 32, b). 256 threads = 4 waves -> 2 blocks/CU.
// out1: wave w: n in {3w..3w+2}; frags fi,fj in {0,1}. acc1[3][2][2].
// out2: wave w: ig=w&1 (i half), jjs=(w>>1)*16 (j half); acc2[16]; h in-register.
__global__ __launch_bounds__(256, 2)
void fused_out(const u16* __restrict__ KEYP, const u16* __restrict__ STb,
               const float* __restrict__ SU, const float* __restrict__ TV,
               const u16* __restrict__ F3WB, const float* __restrict__ f3b,
               float* __restrict__ out)
{
    __shared__ __align__(16) char smem[50944];
    u16*   keyc = (u16*)smem;              // [12][32][40] bf16  30720B
    u16*   tc   = (u16*)(smem + 30720);    // [32][40]           2560B
    float* suc  = (float*)(smem + 33280);  // [32][36]           4608B
    float* tvc  = (float*)(smem + 37888);  // [32][36]           4608B
    u16*   f3c  = (u16*)(smem + 42496);    // [16][264]          8448B
    float* mg   = (float*)smem;            // merge reuse: [6] x stride 1156 f32 (27744B <= 30720)

    const int tid = threadIdx.x;
    const int w = tid >> 6, l = tid & 63;
    const int b  = blockIdx.z;
    const int i0 = blockIdx.y * 32;
    const int j0 = blockIdx.x * 32;
    const int lr = l & 15, lg = l >> 4;
    const int ig = w & 1, jjs = (w >> 1) * 16;   // out2 roles

    { // stage f3c once (read after first in-loop barrier)
        int r = tid >> 4, q = tid & 15;          // 16 rows x 16 granules? 16x256 u16 = 512 granules/2... 256 thr x 2
        // 16 rows x 256 u16 = 4096 u16 = 512 x s16x8; do 2 per thread
#pragma unroll
        for (int rr = 0; rr < 2; ++rr) {
            int g = tid + 256 * rr;              // 0..511
            int row = g >> 5, qq = g & 31;       // 32 granules per row
            *(s16x8*)&f3c[row * 264 + qq * 8] = *(const s16x8*)&F3WB[row * 256 + qq * 8];
        }
        (void)r; (void)q;
    }

    f32x4 acc1[3][2][2] = {};
    f32x4 acc2[16]      = {};

    for (int e0 = 0; e0 < 256; e0 += 32) {
        __syncthreads();
        // keyc: 12n x 32i x 4q granules = 1536, 6 per thread
#pragma unroll
        for (int rr = 0; rr < 6; ++rr) {
            int g = tid + 256 * rr;
            int n = g >> 7, ii = (g >> 2) & 31, qq = g & 3;
            *(s16x8*)&keyc[(n * 32 + ii) * 40 + qq * 8] =
                *(const s16x8*)&KEYP[(size_t)n * 262144 + (size_t)(b * 512 + i0 + ii) * 256 + e0 + qq * 8];
        }
        if (tid < 128) {   // t tile: 32 rows x 4 granules (bf16 cols 256.. of STb)
            int rrow = tid >> 2, qq = tid & 3;
            *(s16x8*)&tc[rrow * 40 + qq * 8] =
                *(const s16x8*)&STb[(size_t)(b * 512 + j0 + rrow) * 512 + 256 + e0 + qq * 8];
        }
        {                  // su tile f32: 32 rows x 8 f32x4
            int rrow = tid >> 3, qq = tid & 7;
            *(f32x4*)&suc[rrow * 36 + qq * 4] =
                *(const f32x4*)&SU[(size_t)(b * 512 + i0 + rrow) * 256 + e0 + qq * 4];
            *(f32x4*)&tvc[rrow * 36 + qq * 4] =
                *(const f32x4*)&TV[(size_t)(b * 512 + j0 + rrow) * 256 + e0 + qq * 4];
        }
        __syncthreads();

        // ---- out1: 12 mfma ----
        s16x8 tf[2];
        tf[0] = *(const s16x8*)&tc[(lr     ) * 40 + lg * 8];
        tf[1] = *(const s16x8*)&tc[(16 + lr) * 40 + lg * 8];
#pragma unroll
        for (int a = 0; a < 3; ++a) {
            int n = 3 * w + a;
            s16x8 kf0 = *(const s16x8*)&keyc[(n * 32      + lr) * 40 + lg * 8];
            s16x8 kf1 = *(const s16x8*)&keyc[(n * 32 + 16 + lr) * 40 + lg * 8];
            acc1[a][0][0] = mfma_bf16(kf0, tf[0], acc1[a][0][0]);
            acc1[a][0][1] = mfma_bf16(kf0, tf[1], acc1[a][0][1]);
            acc1[a][1][0] = mfma_bf16(kf1, tf[0], acc1[a][1][0]);
            acc1[a][1][1] = mfma_bf16(kf1, tf[1], acc1[a][1][1]);
        }

        // ---- out2: h in-register + 16 mfma ----
        f32x4 s0 = *(const f32x4*)&suc[(ig * 16 + lr) * 36 + lg * 8];
        f32x4 s1 = *(const f32x4*)&suc[(ig * 16 + lr) * 36 + lg * 8 + 4];
        s16x8 f3fr = *(const s16x8*)&f3c[lr * 264 + e0 + lg * 8];
#pragma unroll
        for (int jj = 0; jj < 16; ++jj) {
            int j = jjs + jj;
            f32x4 t0 = *(const f32x4*)&tvc[j * 36 + lg * 8];
            f32x4 t1 = *(const f32x4*)&tvc[j * 36 + lg * 8 + 4];
            bf16x8 hv;
            hv[0] = (__bf16)fmaxf(s0[0] + t0[0], 0.f);
            hv[1] = (__bf16)fmaxf(s0[1] + t0[1], 0.f);
            hv[2] = (__bf16)fmaxf(s0[2] + t0[2], 0.f);
            hv[3] = (__bf16)fmaxf(s0[3] + t0[3], 0.f);
            hv[4] = (__bf16)fmaxf(s1[0] + t1[0], 0.f);
            hv[5] = (__bf16)fmaxf(s1[1] + t1[1], 0.f);
            hv[6] = (__bf16)fmaxf(s1[2] + t1[2], 0.f);
            hv[7] = (__bf16)fmaxf(s1[3] + t1[3], 0.f);
            acc2[jj] = mfma_bf16v(hv, f3fr, acc2[jj]);
        }
    }

    // ---- merge out2 D[n=lr][i][j] into out1 layout via LDS, then store ----
    // mg layout: n' * 1156 + i * 36 + j  (floats); 6 n per chunk
#pragma unroll
    for (int nc = 0; nc < 2; ++nc) {
        __syncthreads();
        int nb = nc * 6;
        int lrp = lr - nb;
        if (lrp >= 0 && lrp < 6) {  // writers: all waves, lanes with n=lr in chunk
#pragma unroll
            for (int r = 0; r < 4; ++r) {
                int i = ig * 16 + lg * 4 + r;
#pragma unroll
                for (int q = 0; q < 4; ++q) {
                    f32x4 v;
                    v[0] = acc2[4 * q + 0][r];
                    v[1] = acc2[4 * q + 1][r];
                    v[2] = acc2[4 * q + 2][r];
                    v[3] = acc2[4 * q + 3][r];
                    *(f32x4*)&mg[lrp * 1156 + i * 36 + jjs + 4 * q] = v;
                }
            }
        }
        __syncthreads();
        if ((w >> 1) == nc) {  // readers: waves whose n-range is this chunk
#pragma unroll
            for (int a = 0; a < 3; ++a) {
                int n = 3 * w + a;
                float fb = f3b[n];
#pragma unroll
                for (int fi = 0; fi < 2; ++fi) {
#pragma unroll
                    for (int r = 0; r < 4; ++r) {
                        int i = fi * 16 + lg * 4 + r;
#pragma unroll
                        for (int fj = 0; fj < 2; ++fj) {
                            int j = fj * 16 + lr;
                            float v = acc1[a][fi][fj][r] + mg[(n - nb) * 1156 + i * 36 + j] + fb;
                            out[(((size_t)(b * 512 + i0 + i)) * 12 + n) * 512 + j0 + j] = v;
                        }
                    }
                }
            }
        }
    }
}

extern "C" void kernel_launch(void* const* d_in, const int* in_sizes, int n_in,
                              void* d_out, int out_size, void* d_ws, size_t ws_size,
                              hipStream_t stream)
{
    const float* x   = (const float*)d_in[0];
    const float* sW  = (const float*)d_in[1];
    const float* sb  = (const float*)d_in[2];
    const float* tW  = (const float*)d_in[3];
    const float* tb  = (const float*)d_in[4];
    const float* f2W = (const float*)d_in[5];
    const float* f2b = (const float*)d_in[6];
    const float* f3W = (const float*)d_in[7];
    const float* f3b = (const float*)d_in[8];
    const float* blW = (const float*)d_in[9];
    float* out = (float*)d_out;

    char* p = (char*)d_ws;
    u16*   xb    = (u16*)p;   p += 1572864;   // [1024][768] bf16
    u16*   wstb  = (u16*)p;   p += 786432;    // [512][768] bf16 (sW;tW)
    float* sbtb  = (float*)p; p += 2048;      // [512] f32
    u16*   STb   = (u16*)p;   p += 1048576;   // [1024][512] bf16 (s|t)
    u16*   blkw  = (u16*)p;   p += 1703936;   // [3328][256] bf16 (blW perm ; Wu)
    u16*   KEYP  = (u16*)p;   p += 6291456;   // [12][1024][256] bf16
    float* SUp   = (float*)p; p += 1048576;   // [1024][256] f32
    u16*   f2wvb = (u16*)p;   p += 131072;    // [256][256] bf16 (Wv)
    float* TVp   = (float*)p; p += 1048576;   // [1024][256] f32 (tv + f2b)
    u16*   f3wbg = (u16*)p;   p += 8192;      // [16][256] bf16 (f3W zero-padded)

    conv_kernel<<<2053, 256, 0, stream>>>(x, sW, tW, sb, tb, f2W, blW, f3W,
                                          xb, wstb, sbtb, blkw, f2wvb, f3wbg);
    gemm_mfma<0><<<dim3(8, 16),  256, 0, stream>>>(xb, 768, wstb, 768, sbtb, STb, nullptr, 768);
    gemm_mfma<1><<<dim3(52, 16), 256, 0, stream>>>(STb, 512, blkw, 256, nullptr, KEYP, SUp, 256);
    gemm_mfma<2><<<dim3(4, 16),  256, 0, stream>>>(STb + 256, 512, f2wvb, 256, f2b, TVp, nullptr, 256);
    fused_out<<<dim3(16, 16, 2), 256, 0, stream>>>(KEYP, STb, SUp, TVp, f3wbg, f3b, out);
}

// Round 5
// 52.533 us; speedup vs baseline: 4.8633x; 1.3266x over previous
//
#include <hip/hip_runtime.h>
#include <hip/hip_bf16.h>

// B=2, L=512, H_IN=768, E=256, N=12. M = B*L = 1024.
// out[b,i,n,j] = sum_e key[b,i,e,n]*t[b,j,e]
//             + sum_e relu(su[b,i,e]+tv[b,j,e]+f2b[e])*f3W[n,e] + f3b[n]
// All intermediates fp16 (better mantissa than bf16; packed VALU for h).

typedef unsigned short u16;
typedef __attribute__((ext_vector_type(8))) short    s16x8;
typedef __attribute__((ext_vector_type(8))) _Float16 f16x8;
typedef __attribute__((ext_vector_type(4))) float    f32x4;

__device__ inline u16 f2h(float f) { return __builtin_bit_cast(u16, (_Float16)f); }

__device__ inline f32x4 mfma_f16(s16x8 a, s16x8 b, f32x4 c) {
    return __builtin_amdgcn_mfma_f32_16x16x32_f16(
        __builtin_bit_cast(f16x8, a), __builtin_bit_cast(f16x8, b), c, 0, 0, 0);
}
__device__ inline f32x4 mfma_f16v(f16x8 a, s16x8 b, f32x4 c) {
    return __builtin_amdgcn_mfma_f32_16x16x32_f16(a, __builtin_bit_cast(f16x8, b), c, 0, 0, 0);
}

// ---------------- conversion / permutation kernel (float4-wide) ----------------
__global__ __launch_bounds__(256)
void conv_kernel(const float* __restrict__ x, const float* __restrict__ sW,
                 const float* __restrict__ tW, const float* __restrict__ sb,
                 const float* __restrict__ tb, const float* __restrict__ f2W,
                 const float* __restrict__ blW, const float* __restrict__ f3W,
                 u16* __restrict__ xb, u16* __restrict__ wstb, float* __restrict__ sbtb,
                 u16* __restrict__ blkw, u16* __restrict__ f2wvb, u16* __restrict__ f3wb)
{
    int idx = blockIdx.x * 256 + threadIdx.x;
    if (idx >= 525440) return;
    float4 v;
    u16* dst;
    if (idx < 196608) {                       // xb [1024][768]
        v = *(const float4*)&x[idx * 4];
        dst = &xb[idx * 4];
    } else if (idx < 294912) {                // wstb: rows 0..255 sW, 256..511 tW
        int i4 = (idx - 196608) * 4;
        int row = i4 / 768, k = i4 - row * 768;
        const float* src = (row < 256) ? &sW[row * 768 + k] : &tW[(row - 256) * 768 + k];
        v = *(const float4*)src;
        dst = &wstb[i4];
    } else if (idx < 295040) {                // sbtb f32
        int i4 = (idx - 294912) * 4;
        float4 s = (i4 < 256) ? *(const float4*)&sb[i4] : *(const float4*)&tb[i4 - 256];
        *(float4*)&sbtb[i4] = s;
        return;
    } else if (idx < 508032) {                // blkw [3328][256]: r<3072: n=r>>8,e=r&255 <- blW[e*12+n]; else Wu
        int i4 = (idx - 295040) * 4;
        int r = i4 >> 8, k = i4 & 255;
        const float* src;
        if (r < 3072) { int n = r >> 8, e = r & 255; src = &blW[(e * 12 + n) * 256 + k]; }
        else           { src = &f2W[(r - 3072) * 512 + k]; }
        v = *(const float4*)src;
        dst = &blkw[i4];
    } else if (idx < 524416) {                // f2wvb [256][256] = f2W[:,256:]
        int i4 = (idx - 508032) * 4;
        int e = i4 >> 8, k = i4 & 255;
        v = *(const float4*)&f2W[e * 512 + 256 + k];
        dst = &f2wvb[i4];
    } else {                                  // f3wb [16][256], rows 12..15 zero
        int i4 = (idx - 524416) * 4;
        int row = i4 >> 8, e = i4 & 255;
        if (row < 12) v = *(const float4*)&f3W[row * 256 + e];
        else          v = make_float4(0.f, 0.f, 0.f, 0.f);
        dst = &f3wb[i4];
    }
    ushort4 o;
    o.x = f2h(v.x); o.y = f2h(v.y); o.z = f2h(v.z); o.w = f2h(v.w);
    *(ushort4*)dst = o;
}

// ---------------- f16 MFMA GEMM: C = epilogue(A[M][K] * BT[N][K]^T) ----------------
// 64x64 tile, BK=64, 256 threads (4 waves, 32x32 quadrant each), T14 reg-prefetch.
template<int MODE>
__global__ __launch_bounds__(256, 2)
void gemm_mfma(const u16* __restrict__ A, int lda,
               const u16* __restrict__ BT, int ldb,
               const float* __restrict__ bias,
               void* __restrict__ out0, void* __restrict__ out1p, int K)
{
    __shared__ u16 As[64 * 72];
    __shared__ u16 Bs[64 * 72];
    const int tid = threadIdx.x;
    const int m0 = blockIdx.y * 64, n0 = blockIdx.x * 64;
    const int w = tid >> 6, l = tid & 63;
    const int wr = (w >> 1) * 32, wc = (w & 1) * 32;
    const int lr = l & 15, lg = l >> 4;
    const int srow = tid >> 2, kq = tid & 3;

    const u16* ap = &A [(size_t)(m0 + srow) * lda];
    const u16* bp = &BT[(size_t)(n0 + srow) * ldb];
    s16x8 ra0 = *(const s16x8*)&ap[kq * 8];
    s16x8 ra1 = *(const s16x8*)&ap[(kq + 4) * 8];
    s16x8 rb0 = *(const s16x8*)&bp[kq * 8];
    s16x8 rb1 = *(const s16x8*)&bp[(kq + 4) * 8];

    f32x4 acc[2][2] = {};
    for (int k0 = 0; k0 < K; k0 += 64) {
        __syncthreads();
        *(s16x8*)&As[srow * 72 + kq * 8]       = ra0;
        *(s16x8*)&As[srow * 72 + (kq + 4) * 8] = ra1;
        *(s16x8*)&Bs[srow * 72 + kq * 8]       = rb0;
        *(s16x8*)&Bs[srow * 72 + (kq + 4) * 8] = rb1;
        __syncthreads();
        if (k0 + 64 < K) {   // prefetch next K-tile into regs (latency hides under MFMA)
            ra0 = *(const s16x8*)&ap[k0 + 64 + kq * 8];
            ra1 = *(const s16x8*)&ap[k0 + 64 + (kq + 4) * 8];
            rb0 = *(const s16x8*)&bp[k0 + 64 + kq * 8];
            rb1 = *(const s16x8*)&bp[k0 + 64 + (kq + 4) * 8];
        }
#pragma unroll
        for (int kk = 0; kk < 64; kk += 32) {
            s16x8 af[2], bf[2];
            af[0] = *(const s16x8*)&As[(wr      + lr) * 72 + kk + lg * 8];
            af[1] = *(const s16x8*)&As[(wr + 16 + lr) * 72 + kk + lg * 8];
            bf[0] = *(const s16x8*)&Bs[(wc      + lr) * 72 + kk + lg * 8];
            bf[1] = *(const s16x8*)&Bs[(wc + 16 + lr) * 72 + kk + lg * 8];
#pragma unroll
            for (int fi = 0; fi < 2; ++fi)
#pragma unroll
                for (int fj = 0; fj < 2; ++fj)
                    acc[fi][fj] = mfma_f16(af[fi], bf[fj], acc[fi][fj]);
        }
    }
#pragma unroll
    for (int fi = 0; fi < 2; ++fi) {
#pragma unroll
        for (int fj = 0; fj < 2; ++fj) {
#pragma unroll
            for (int r = 0; r < 4; ++r) {
                int grow = m0 + wr + fi * 16 + lg * 4 + r;
                int gcol = n0 + wc + fj * 16 + lr;
                float v = acc[fi][fj][r];
                if (MODE == 0) {
                    v = fmaxf(v + bias[gcol], 0.f);
                    ((u16*)out0)[(size_t)grow * 512 + gcol] = f2h(v);
                } else if (MODE == 1) {
                    if (gcol < 3072) {
                        int n = gcol >> 8, e = gcol & 255;
                        ((u16*)out0)[(size_t)n * 262144 + (size_t)grow * 256 + e] = f2h(v);
                    } else {
                        ((u16*)out1p)[(size_t)grow * 256 + (gcol - 3072)] = f2h(v);
                    }
                } else {
                    ((u16*)out0)[(size_t)grow * 256 + gcol] = f2h(v + bias[gcol]);
                }
            }
        }
    }
}

// ---------------- fused output kernel ----------------
// grid (16 j-tiles, 32 i-tiles, 2 b): block = 16i x 32j, 256 thr = 4 waves, 30.2KB LDS.
// out1: wave w owns n in {3w..3w+2}: acc1[3][2] (fj j-halves).
// out2: wave w owns j in w*8..w*8+7: acc2[8]; h built with packed f16 ops.
// T14: issue global loads for iter k+1 right after barrier; commit regs->LDS next iter.
__global__ __launch_bounds__(256, 4)
void fused_out(const u16* __restrict__ KEYP, const u16* __restrict__ STb,
               const u16* __restrict__ SUh, const u16* __restrict__ TVh,
               const u16* __restrict__ F3WH, const float* __restrict__ f3b,
               float* __restrict__ out)
{
    __shared__ __align__(16) char smem[30208];
    u16* lds = (u16*)smem;
    // u16-offsets: keyc [12][16][40] @0 | tc [32][40] @7680 | suc [16][40] @8960
    //              tvc [32][40] @9600 | f3c [16][264] @10880 (ends 15104 u16 = 30208B)
    const int KEYC = 0, TC = 7680, SUC = 8960, TVC = 9600, F3C = 10880;

    const int tid = threadIdx.x;
    const int w = tid >> 6, l = tid & 63;
    const int b  = blockIdx.z;
    const int i0 = blockIdx.y * 16;
    const int j0 = blockIdx.x * 32;
    const int lr = l & 15, lg = l >> 4;

    // staging descriptors (1088 granules of 16B; rr=4 only for tid<64)
    const u16* sb_[5]; int do_[5];
#pragma unroll
    for (int rr = 0; rr < 5; ++rr) {
        int g = tid + 256 * rr;
        const u16* s = nullptr; int d = 0;
        if (g < 768) {
            int n = g >> 6, ii = (g >> 2) & 15, qq = g & 3;
            s = KEYP + (size_t)n * 262144 + (size_t)(b * 512 + i0 + ii) * 256 + qq * 8;
            d = KEYC + (n * 16 + ii) * 40 + qq * 8;
        } else if (g < 896) {
            int q = g - 768, jj = q >> 2, qq = q & 3;
            s = STb + (size_t)(b * 512 + j0 + jj) * 512 + 256 + qq * 8;
            d = TC + jj * 40 + qq * 8;
        } else if (g < 960) {
            int q = g - 896, ii = q >> 2, qq = q & 3;
            s = SUh + (size_t)(b * 512 + i0 + ii) * 256 + qq * 8;
            d = SUC + ii * 40 + qq * 8;
        } else {
            int q = g - 960, jj = q >> 2, qq = q & 3;
            s = TVh + (size_t)(b * 512 + j0 + jj) * 256 + qq * 8;
            d = TVC + jj * 40 + qq * 8;
        }
        sb_[rr] = s; do_[rr] = d;
    }
    const bool v4 = (tid < 64);

    // f3c staged once (first reads happen after first barrier pair)
#pragma unroll
    for (int rr = 0; rr < 2; ++rr) {
        int g = tid + 256 * rr;
        int row = g >> 5, qq = g & 31;
        *(s16x8*)&lds[F3C + row * 264 + qq * 8] = *(const s16x8*)&F3WH[row * 256 + qq * 8];
    }

    s16x8 st0, st1, st2, st3, st4 = {};
    f32x4 acc1[3][2] = {};
    f32x4 acc2[8]    = {};

    // prologue issue for e0=0
    st0 = *(const s16x8*)(sb_[0]);
    st1 = *(const s16x8*)(sb_[1]);
    st2 = *(const s16x8*)(sb_[2]);
    st3 = *(const s16x8*)(sb_[3]);
    if (v4) st4 = *(const s16x8*)(sb_[4]);

    for (int it = 0; it < 8; ++it) {
        const int e0 = it * 32;
        __syncthreads();
        *(s16x8*)&lds[do_[0]] = st0;
        *(s16x8*)&lds[do_[1]] = st1;
        *(s16x8*)&lds[do_[2]] = st2;
        *(s16x8*)&lds[do_[3]] = st3;
        if (v4) *(s16x8*)&lds[do_[4]] = st4;
        __syncthreads();
        if (it < 7) {   // issue next tile; latency hides under compute below
            st0 = *(const s16x8*)(sb_[0] + e0 + 32);
            st1 = *(const s16x8*)(sb_[1] + e0 + 32);
            st2 = *(const s16x8*)(sb_[2] + e0 + 32);
            st3 = *(const s16x8*)(sb_[3] + e0 + 32);
            if (v4) st4 = *(const s16x8*)(sb_[4] + e0 + 32);
        }
        // ---- out1: 6 mfma ----
        s16x8 tf0 = *(const s16x8*)&lds[TC + lr * 40 + lg * 8];
        s16x8 tf1 = *(const s16x8*)&lds[TC + (16 + lr) * 40 + lg * 8];
#pragma unroll
        for (int a = 0; a < 3; ++a) {
            int n = 3 * w + a;
            s16x8 kf = *(const s16x8*)&lds[KEYC + (n * 16 + lr) * 40 + lg * 8];
            acc1[a][0] = mfma_f16(kf, tf0, acc1[a][0]);
            acc1[a][1] = mfma_f16(kf, tf1, acc1[a][1]);
        }
        // ---- out2: packed-f16 h + 8 mfma ----
        f16x8 sv = __builtin_bit_cast(f16x8, *(const s16x8*)&lds[SUC + lr * 40 + lg * 8]);
        s16x8 f3fr = *(const s16x8*)&lds[F3C + lr * 264 + e0 + lg * 8];
#pragma unroll
        for (int jj = 0; jj < 8; ++jj) {
            int j = w * 8 + jj;
            f16x8 tv8 = __builtin_bit_cast(f16x8, *(const s16x8*)&lds[TVC + j * 40 + lg * 8]);
            f16x8 hv = sv + tv8;
#pragma unroll
            for (int q = 0; q < 8; ++q)
                hv[q] = hv[q] > (_Float16)0.f ? hv[q] : (_Float16)0.f;
            acc2[jj] = mfma_f16v(hv, f3fr, acc2[jj]);
        }
    }

    // ---- merge out2 D[n=lr][i][j] into out1 layout via LDS (overlay), then store ----
    __syncthreads();
    float* mg = (float*)smem;   // [12] x stride 580 f32; i stride 36; 27.8KB
    if (lr < 12) {
#pragma unroll
        for (int r = 0; r < 4; ++r) {
            int i = lg * 4 + r;
            f32x4 v0, v1;
            v0[0] = acc2[0][r]; v0[1] = acc2[1][r]; v0[2] = acc2[2][r]; v0[3] = acc2[3][r];
            v1[0] = acc2[4][r]; v1[1] = acc2[5][r]; v1[2] = acc2[6][r]; v1[3] = acc2[7][r];
            *(f32x4*)&mg[lr * 580 + i * 36 + w * 8]     = v0;
            *(f32x4*)&mg[lr * 580 + i * 36 + w * 8 + 4] = v1;
        }
    }
    __syncthreads();
#pragma unroll
    for (int a = 0; a < 3; ++a) {
        int n = 3 * w + a;
        float fb = f3b[n];
#pragma unroll
        for (int fj = 0; fj < 2; ++fj) {
            int j = fj * 16 + lr;
#pragma unroll
            for (int r = 0; r < 4; ++r) {
                int i = lg * 4 + r;
                float vv = acc1[a][fj][r] + mg[n * 580 + i * 36 + j] + fb;
                out[(((size_t)(b * 512 + i0 + i)) * 12 + n) * 512 + j0 + j] = vv;
            }
        }
    }
}

extern "C" void kernel_launch(void* const* d_in, const int* in_sizes, int n_in,
                              void* d_out, int out_size, void* d_ws, size_t ws_size,
                              hipStream_t stream)
{
    const float* x   = (const float*)d_in[0];
    const float* sW  = (const float*)d_in[1];
    const float* sb  = (const float*)d_in[2];
    const float* tW  = (const float*)d_in[3];
    const float* tb  = (const float*)d_in[4];
    const float* f2W = (const float*)d_in[5];
    const float* f2b = (const float*)d_in[6];
    const float* f3W = (const float*)d_in[7];
    const float* f3b = (const float*)d_in[8];
    const float* blW = (const float*)d_in[9];
    float* out = (float*)d_out;

    char* p = (char*)d_ws;
    u16*   xb    = (u16*)p;   p += 1572864;   // [1024][768] f16
    u16*   wstb  = (u16*)p;   p += 786432;    // [512][768] f16 (sW;tW)
    float* sbtb  = (float*)p; p += 2048;      // [512] f32
    u16*   STb   = (u16*)p;   p += 1048576;   // [1024][512] f16 (s|t)
    u16*   blkw  = (u16*)p;   p += 1703936;   // [3328][256] f16 (blW perm ; Wu)
    u16*   KEYP  = (u16*)p;   p += 6291456;   // [12][1024][256] f16
    u16*   SUp   = (u16*)p;   p += 524288;    // [1024][256] f16
    u16*   f2wvb = (u16*)p;   p += 131072;    // [256][256] f16 (Wv)
    u16*   TVp   = (u16*)p;   p += 524288;    // [1024][256] f16 (tv + f2b)
    u16*   f3wbg = (u16*)p;   p += 8192;      // [16][256] f16 (f3W zero-padded)

    conv_kernel<<<2053, 256, 0, stream>>>(x, sW, tW, sb, tb, f2W, blW, f3W,
                                          xb, wstb, sbtb, blkw, f2wvb, f3wbg);
    gemm_mfma<0><<<dim3(8, 16),  256, 0, stream>>>(xb, 768, wstb, 768, sbtb, STb, nullptr, 768);
    gemm_mfma<1><<<dim3(52, 16), 256, 0, stream>>>(STb, 512, blkw, 256, nullptr, KEYP, SUp, 256);
    gemm_mfma<2><<<dim3(4, 16),  256, 0, stream>>>(STb + 256, 512, f2wvb, 256, f2b, TVp, nullptr, 256);
    fused_out<<<dim3(16, 32, 2), 256, 0, stream>>>(KEYP, STb, SUp, TVp, f3wbg, f3b, out);
}